// Round 1
// baseline (29698.837 us; speedup 1.0000x reference)
//
#include <hip/hip_runtime.h>
#include <math.h>

namespace {

constexpr int B_ = 128, S_ = 800, H_ = 512, E_ = 256, V_ = 34, T_ = 128;

__device__ __forceinline__ float sigf(float x) { return 1.f / (1.f + expf(-x)); }

__device__ __forceinline__ float dot8(float4 a0, float4 a1, float4 b0, float4 b1) {
    return a0.x * b0.x + a0.y * b0.y + a0.z * b0.z + a0.w * b0.w +
           a1.x * b1.x + a1.y * b1.y + a1.z * b1.z + a1.w * b1.w;
}

// ---------------- init: zero state, ctx0 = key[:,0,:] ----------------
__launch_bounds__(256)
__global__ void k_init(const float* __restrict__ key,
                       float* __restrict__ c0, float* __restrict__ c1,
                       float* __restrict__ h0a, float* __restrict__ h0b,
                       float* __restrict__ h1a, float* __restrict__ h1b,
                       float* __restrict__ ctxa, float* __restrict__ ctxb,
                       float* __restrict__ masked) {
    int i = blockIdx.x * 256 + threadIdx.x;   // 0..65535
    int b = i >> 9, h = i & 511;
    c0[i] = 0.f; c1[i] = 0.f;
    h0a[i] = 0.f; h0b[i] = 0.f;
    h1a[i] = 0.f; h1b[i] = 0.f;
    ctxb[i] = 0.f; masked[i] = 0.f;
    ctxa[i] = key[(size_t)b * S_ * H_ + h];
}

// ------------- masked-value precompute: masked[b][h] = 1e-9 * sum_{s>=len} value -------------
__launch_bounds__(256)
__global__ void k_mask(const float* __restrict__ value, const int* __restrict__ lens,
                       float* __restrict__ masked) {
    int strip = blockIdx.x, b = blockIdx.y;
    int len = lens[b];
    int s0 = strip * 100, s1 = s0 + 100;
    int sb = s0 > len ? s0 : len;
    if (sb >= s1) return;
    int h2 = threadIdx.x * 2;
    const float* vb = value + (size_t)b * S_ * H_ + h2;
    float a0 = 0.f, a1 = 0.f;
    for (int s = sb; s < s1; ++s) {
        float2 v = *(const float2*)(vb + (size_t)s * H_);
        a0 += v.x; a1 += v.y;
    }
    atomicAdd(&masked[b * H_ + h2], a0 * 1e-9f);
    atomicAdd(&masked[b * H_ + h2 + 1], a1 * 1e-9f);
}

// ---------------- LSTM cell 1: gates = [ctx|emb]@Wih1^T + h0@Whh1^T + b1 ----------------
// grid 512 (one h per WG), 256 threads: b = tid&127, kh = tid>>7 splits K
__launch_bounds__(256)
__global__ void k_lstm1(const float* __restrict__ ctx, const float* __restrict__ h0in,
                        const int* __restrict__ decode, const float* __restrict__ emb,
                        const float* __restrict__ Wih, const float* __restrict__ Whh,
                        const float* __restrict__ bias,
                        float* __restrict__ c0, float* __restrict__ h0out, int t) {
    __shared__ float xl[128 * 66];
    __shared__ int tokl[128];
    const int tid = threadIdx.x;
    const int h = blockIdx.x;           // 0..511, wave-uniform
    if (tid < 128) tokl[tid] = decode[tid * T_ + t];
    const int b = tid & 127;
    const int kh = tid >> 7;            // 0/1: K-half
    float acc0 = 0, acc1 = 0, acc2 = 0, acc3 = 0;
    __syncthreads();
    for (int c = 0; c < 20; ++c) {      // K = 1280 in chunks of 64
        int kbase = c * 64;
        // stage x chunk [128][64] into LDS (pad stride 66)
#pragma unroll
        for (int i = 0; i < 8; ++i) {
            int f4 = tid + i * 256;     // 0..2047 float4 units
            int bb = f4 >> 4;
            int kk = (f4 & 15) << 2;
            int k = kbase + kk;
            const float* src;
            if (k < 512)      src = ctx  + (size_t)bb * H_ + k;
            else if (k < 768) src = emb  + (size_t)tokl[bb] * E_ + (k - 512);
            else              src = h0in + (size_t)bb * H_ + (k - 768);
            float4 v = *(const float4*)src;
            float* d = &xl[bb * 66 + kk];
            *(float2*)d       = make_float2(v.x, v.y);
            *(float2*)(d + 2) = make_float2(v.z, v.w);
        }
        __syncthreads();
        const float* xrow = &xl[b * 66 + kh * 32];
        if (kbase < 768) {
            int ko = kbase + kh * 32;
            const float* w0 = Wih + (size_t)(0 * H_ + h) * 768 + ko;
            const float* w1 = Wih + (size_t)(1 * H_ + h) * 768 + ko;
            const float* w2 = Wih + (size_t)(2 * H_ + h) * 768 + ko;
            const float* w3 = Wih + (size_t)(3 * H_ + h) * 768 + ko;
#pragma unroll
            for (int q = 0; q < 8; ++q) {
                int kk = q * 4;
                float2 xa = *(const float2*)(xrow + kk);
                float2 xb = *(const float2*)(xrow + kk + 2);
                float4 w;
                w = *(const float4*)(w0 + kk); acc0 += xa.x * w.x + xa.y * w.y + xb.x * w.z + xb.y * w.w;
                w = *(const float4*)(w1 + kk); acc1 += xa.x * w.x + xa.y * w.y + xb.x * w.z + xb.y * w.w;
                w = *(const float4*)(w2 + kk); acc2 += xa.x * w.x + xa.y * w.y + xb.x * w.z + xb.y * w.w;
                w = *(const float4*)(w3 + kk); acc3 += xa.x * w.x + xa.y * w.y + xb.x * w.z + xb.y * w.w;
            }
        } else {
            int ko = (kbase - 768) + kh * 32;
            const float* w0 = Whh + (size_t)(0 * H_ + h) * 512 + ko;
            const float* w1 = Whh + (size_t)(1 * H_ + h) * 512 + ko;
            const float* w2 = Whh + (size_t)(2 * H_ + h) * 512 + ko;
            const float* w3 = Whh + (size_t)(3 * H_ + h) * 512 + ko;
#pragma unroll
            for (int q = 0; q < 8; ++q) {
                int kk = q * 4;
                float2 xa = *(const float2*)(xrow + kk);
                float2 xb = *(const float2*)(xrow + kk + 2);
                float4 w;
                w = *(const float4*)(w0 + kk); acc0 += xa.x * w.x + xa.y * w.y + xb.x * w.z + xb.y * w.w;
                w = *(const float4*)(w1 + kk); acc1 += xa.x * w.x + xa.y * w.y + xb.x * w.z + xb.y * w.w;
                w = *(const float4*)(w2 + kk); acc2 += xa.x * w.x + xa.y * w.y + xb.x * w.z + xb.y * w.w;
                w = *(const float4*)(w3 + kk); acc3 += xa.x * w.x + xa.y * w.y + xb.x * w.z + xb.y * w.w;
            }
        }
        __syncthreads();
    }
    // combine the two K-halves, then cell update
    if (kh == 1) {
        float* r = &xl[b * 4];
        r[0] = acc0; r[1] = acc1; r[2] = acc2; r[3] = acc3;
    }
    __syncthreads();
    if (kh == 0) {
        const float* r = &xl[b * 4];
        acc0 += r[0]; acc1 += r[1]; acc2 += r[2]; acc3 += r[3];
        acc0 += bias[h]; acc1 += bias[512 + h]; acc2 += bias[1024 + h]; acc3 += bias[1536 + h];
        float i_ = sigf(acc0), f_ = sigf(acc1), g_ = tanhf(acc2), o_ = sigf(acc3);
        int idx = b * H_ + h;
        float cn = f_ * c0[idx] + i_ * g_;
        c0[idx] = cn;
        h0out[idx] = o_ * tanhf(cn);
    }
}

// ---------------- LSTM cell 2: gates = h0new@Wih2^T + h1@Whh2^T + b2 ----------------
__launch_bounds__(256)
__global__ void k_lstm2(const float* __restrict__ x2, const float* __restrict__ h1in,
                        const float* __restrict__ Wih, const float* __restrict__ Whh,
                        const float* __restrict__ bias,
                        float* __restrict__ c1, float* __restrict__ h1out) {
    __shared__ float xl[128 * 66];
    const int tid = threadIdx.x;
    const int h = blockIdx.x;
    const int b = tid & 127;
    const int kh = tid >> 7;
    float acc0 = 0, acc1 = 0, acc2 = 0, acc3 = 0;
    for (int c = 0; c < 16; ++c) {      // K = 1024
        int kbase = c * 64;
#pragma unroll
        for (int i = 0; i < 8; ++i) {
            int f4 = tid + i * 256;
            int bb = f4 >> 4;
            int kk = (f4 & 15) << 2;
            int k = kbase + kk;
            const float* src = (k < 512) ? x2 + (size_t)bb * H_ + k
                                         : h1in + (size_t)bb * H_ + (k - 512);
            float4 v = *(const float4*)src;
            float* d = &xl[bb * 66 + kk];
            *(float2*)d       = make_float2(v.x, v.y);
            *(float2*)(d + 2) = make_float2(v.z, v.w);
        }
        __syncthreads();
        const float* xrow = &xl[b * 66 + kh * 32];
        const float* W = (kbase < 512) ? Wih : Whh;
        int ko = (kbase < 512 ? kbase : kbase - 512) + kh * 32;
        const float* w0 = W + (size_t)(0 * H_ + h) * 512 + ko;
        const float* w1 = W + (size_t)(1 * H_ + h) * 512 + ko;
        const float* w2 = W + (size_t)(2 * H_ + h) * 512 + ko;
        const float* w3 = W + (size_t)(3 * H_ + h) * 512 + ko;
#pragma unroll
        for (int q = 0; q < 8; ++q) {
            int kk = q * 4;
            float2 xa = *(const float2*)(xrow + kk);
            float2 xb = *(const float2*)(xrow + kk + 2);
            float4 w;
            w = *(const float4*)(w0 + kk); acc0 += xa.x * w.x + xa.y * w.y + xb.x * w.z + xb.y * w.w;
            w = *(const float4*)(w1 + kk); acc1 += xa.x * w.x + xa.y * w.y + xb.x * w.z + xb.y * w.w;
            w = *(const float4*)(w2 + kk); acc2 += xa.x * w.x + xa.y * w.y + xb.x * w.z + xb.y * w.w;
            w = *(const float4*)(w3 + kk); acc3 += xa.x * w.x + xa.y * w.y + xb.x * w.z + xb.y * w.w;
        }
        __syncthreads();
    }
    if (kh == 1) {
        float* r = &xl[b * 4];
        r[0] = acc0; r[1] = acc1; r[2] = acc2; r[3] = acc3;
    }
    __syncthreads();
    if (kh == 0) {
        const float* r = &xl[b * 4];
        acc0 += r[0]; acc1 += r[1]; acc2 += r[2]; acc3 += r[3];
        acc0 += bias[h]; acc1 += bias[512 + h]; acc2 += bias[1024 + h]; acc3 += bias[1536 + h];
        float i_ = sigf(acc0), f_ = sigf(acc1), g_ = tanhf(acc2), o_ = sigf(acc3);
        int idx = b * H_ + h;
        float cn = f_ * c1[idx] + i_ * g_;
        c1[idx] = cn;
        h1out[idx] = o_ * tanhf(cn);
    }
}

// ------- attention scores + (sb==13): logits, zero ctx_next -------
__launch_bounds__(256)
__global__ void k_attn(const float* __restrict__ key, const float* __restrict__ h1,
                       const float* __restrict__ fcW, const float* __restrict__ fcb,
                       float* __restrict__ scores, float* __restrict__ ctx_next,
                       float* __restrict__ out, int t) {
    const int b = blockIdx.y, sb = blockIdx.x;
    const int lane = threadIdx.x & 63, wave = threadIdx.x >> 6;
    const float* h1r = h1 + (size_t)b * H_ + lane * 8;
    float4 ha = *(const float4*)h1r;
    float4 hb = *(const float4*)(h1r + 4);
    if (sb < 13) {
        const float* kb = key + (size_t)b * S_ * H_;
        int s0 = sb * 64 + wave * 16;
#pragma unroll 4
        for (int i = 0; i < 16; ++i) {
            int s = s0 + i;
            if (s < S_) {
                const float* kr = kb + (size_t)s * H_ + lane * 8;
                float4 k0 = *(const float4*)kr, k1 = *(const float4*)(kr + 4);
                float d = dot8(k0, k1, ha, hb);
#pragma unroll
                for (int m = 32; m; m >>= 1) d += __shfl_xor(d, m);
                if (lane == 0) scores[b * S_ + s] = d;
            }
        }
    } else {
        ctx_next[b * H_ + threadIdx.x] = 0.f;
        ctx_next[b * H_ + 256 + threadIdx.x] = 0.f;
        for (int v = wave; v < V_; v += 4) {
            const float* fr = fcW + (size_t)v * H_ + lane * 8;
            float4 f0 = *(const float4*)fr, f1 = *(const float4*)(fr + 4);
            float d = dot8(f0, f1, ha, hb);
#pragma unroll
            for (int m = 32; m; m >>= 1) d += __shfl_xor(d, m);
            if (lane == 0) out[(size_t)b * (T_ * V_) + t * V_ + v] = d + fcb[v];
        }
    }
}

// ------- context: softmax recompute per WG + weighted value sum over s<len -------
__launch_bounds__(256)
__global__ void k_ctx(const float* __restrict__ value, const int* __restrict__ lens,
                      const float* __restrict__ scores, const float* __restrict__ masked,
                      float* __restrict__ ctx_next) {
    __shared__ float sl[800];
    __shared__ float el[104];
    __shared__ float red[8];
    const int b = blockIdx.y, strip = blockIdx.x;
    const int tid = threadIdx.x;
    for (int i = tid; i < 800; i += 256) sl[i] = scores[b * S_ + i];
    __syncthreads();
    float mx = -INFINITY;
    for (int i = tid; i < 800; i += 256) mx = fmaxf(mx, sl[i]);
#pragma unroll
    for (int m = 32; m; m >>= 1) mx = fmaxf(mx, __shfl_xor(mx, m));
    if ((tid & 63) == 0) red[tid >> 6] = mx;
    __syncthreads();
    mx = fmaxf(fmaxf(red[0], red[1]), fmaxf(red[2], red[3]));
    float sm = 0.f;
    for (int i = tid; i < 800; i += 256) sm += expf(sl[i] - mx);
#pragma unroll
    for (int m = 32; m; m >>= 1) sm += __shfl_xor(sm, m);
    if ((tid & 63) == 0) red[4 + (tid >> 6)] = sm;
    __syncthreads();
    sm = red[4] + red[5] + red[6] + red[7];
    const float inv = 1.f / sm;
    const int len = lens[b];
    const int s0 = strip * 100;
    const int s1 = min(s0 + 100, len);
    if (tid < 100) el[tid] = (s0 + tid < s1) ? expf(sl[s0 + tid] - mx) * inv : 0.f;
    __syncthreads();
    const int h2 = tid * 2;
    float a0 = 0.f, a1 = 0.f;
    const float* vb = value + (size_t)b * S_ * H_ + h2;
    for (int s = s0; s < s1; ++s) {
        float e = el[s - s0];
        float2 v = *(const float2*)(vb + (size_t)s * H_);
        a0 += e * v.x; a1 += e * v.y;
    }
    if (strip == 0) { a0 += masked[b * H_ + h2]; a1 += masked[b * H_ + h2 + 1]; }
    if (s1 > s0 || strip == 0) {
        atomicAdd(&ctx_next[b * H_ + h2], a0);
        atomicAdd(&ctx_next[b * H_ + h2 + 1], a1);
    }
}

} // anonymous namespace

extern "C" void kernel_launch(void* const* d_in, const int* in_sizes, int n_in,
                              void* d_out, int out_size, void* d_ws, size_t ws_size,
                              hipStream_t stream) {
    const float* key    = (const float*)d_in[0];
    const float* value  = (const float*)d_in[1];
    const int*   decode = (const int*)d_in[2];
    const int*   lens   = (const int*)d_in[3];
    const float* emb    = (const float*)d_in[4];
    const float* Wih1   = (const float*)d_in[5];
    const float* Whh1   = (const float*)d_in[6];
    const float* b1     = (const float*)d_in[7];
    const float* Wih2   = (const float*)d_in[8];
    const float* Whh2   = (const float*)d_in[9];
    const float* b2     = (const float*)d_in[10];
    const float* fcW    = (const float*)d_in[11];
    const float* fcb    = (const float*)d_in[12];
    float* out = (float*)d_out;

    float* p = (float*)d_ws;
    float* scores = p; p += B_ * S_;
    float* c0     = p; p += B_ * H_;
    float* c1     = p; p += B_ * H_;
    float* masked = p; p += B_ * H_;
    float* h0[2]  = {p, p + B_ * H_}; p += 2 * B_ * H_;
    float* h1[2]  = {p, p + B_ * H_}; p += 2 * B_ * H_;
    float* cx[2]  = {p, p + B_ * H_}; p += 2 * B_ * H_;

    k_init<<<256, 256, 0, stream>>>(key, c0, c1, h0[0], h0[1], h1[0], h1[1],
                                    cx[0], cx[1], masked);
    k_mask<<<dim3(8, B_), 256, 0, stream>>>(value, lens, masked);

    for (int t = 0; t < T_; ++t) {
        int pc = t & 1, pn = pc ^ 1;
        k_lstm1<<<512, 256, 0, stream>>>(cx[pc], h0[pc], decode, emb, Wih1, Whh1, b1,
                                         c0, h0[pn], t);
        k_lstm2<<<512, 256, 0, stream>>>(h0[pn], h1[pc], Wih2, Whh2, b2, c1, h1[pn]);
        k_attn<<<dim3(14, B_), 256, 0, stream>>>(key, h1[pn], fcW, fcb, scores,
                                                 cx[pn], out, t);
        k_ctx<<<dim3(8, B_), 256, 0, stream>>>(value, lens, scores, masked, cx[pn]);
    }
}

// Round 3
// 27614.200 us; speedup vs baseline: 1.0755x; 1.0755x over previous
//
#include <hip/hip_runtime.h>
#include <hip/hip_cooperative_groups.h>
#include <math.h>

namespace cg = cooperative_groups;

namespace {

constexpr int B_ = 128, S_ = 800, H_ = 512, E_ = 256, V_ = 34, T_ = 128;
constexpr int KV_ = B_ * S_ * H_;          // 52428800 elements
constexpr int ST_ = H_ * B_;               // 65536 floats per state buffer

__device__ __forceinline__ float sigf(float x) { return 1.f / (1.f + expf(-x)); }

__device__ __forceinline__ float dot8(float4 a0, float4 a1, float4 b0, float4 b1) {
    return a0.x * b0.x + a0.y * b0.y + a0.z * b0.z + a0.w * b0.w +
           a1.x * b1.x + a1.y * b1.y + a1.z * b1.z + a1.w * b1.w;
}

__device__ __forceinline__ unsigned short f2bf(float f) {   // round-to-nearest-even
    unsigned u = __float_as_uint(f);
    return (unsigned short)((u + 0x7fffu + ((u >> 16) & 1u)) >> 16);
}

__device__ __forceinline__ float bdot(uint4 k, float4 ha, float4 hb) {
    float d;
    d  = __uint_as_float(k.x << 16) * ha.x + __uint_as_float(k.x & 0xffff0000u) * ha.y;
    d += __uint_as_float(k.y << 16) * ha.z + __uint_as_float(k.y & 0xffff0000u) * ha.w;
    d += __uint_as_float(k.z << 16) * hb.x + __uint_as_float(k.z & 0xffff0000u) * hb.y;
    d += __uint_as_float(k.w << 16) * hb.z + __uint_as_float(k.w & 0xffff0000u) * hb.w;
    return d;
}

// ---------- pre-pass: fp32 -> bf16 key/value ----------
__global__ __launch_bounds__(256) void k_pre(const float* __restrict__ key,
                                             const float* __restrict__ value,
                                             unsigned short* __restrict__ kb,
                                             unsigned short* __restrict__ vb) {
    const int n4 = KV_ / 4;
    for (int i = blockIdx.x * 256 + threadIdx.x; i < n4; i += gridDim.x * 256) {
        float4 k4 = ((const float4*)key)[i];
        float4 v4 = ((const float4*)value)[i];
        ushort4 ko, vo;
        ko.x = f2bf(k4.x); ko.y = f2bf(k4.y); ko.z = f2bf(k4.z); ko.w = f2bf(k4.w);
        vo.x = f2bf(v4.x); vo.y = f2bf(v4.y); vo.z = f2bf(v4.z); vo.w = f2bf(v4.w);
        ((ushort4*)kb)[i] = ko;
        ((ushort4*)vb)[i] = vo;
    }
}

// ---------- pre-pass: state init (transposed layouts [h][b]) ----------
__global__ __launch_bounds__(256) void k_init2(const float* __restrict__ key,
                                               float* __restrict__ cxT,
                                               float* __restrict__ h0T,
                                               float* __restrict__ h1T,
                                               float* __restrict__ maskedT) {
    int i = blockIdx.x * 256 + threadIdx.x;     // 0..65535
    int b = i >> 9, h = i & 511;
    cxT[h * B_ + b] = key[(size_t)b * (S_ * H_) + h];   // ctx0 = key[:,0,:]
    cxT[ST_ + i] = 0.f;
    h0T[i] = 0.f; h0T[ST_ + i] = 0.f;
    h1T[i] = 0.f; h1T[ST_ + i] = 0.f;
    maskedT[i] = 0.f;
}

// ---------- pre-pass: maskedT[h][b] = 1e-9 * sum_{s>=len} value[b][s][h] ----------
__global__ __launch_bounds__(256) void k_maskT(const float* __restrict__ value,
                                               const int* __restrict__ lens,
                                               float* __restrict__ maskedT) {
    int strip = blockIdx.x, b = blockIdx.y;
    int len = lens[b];
    int s0 = strip * 100, s1 = s0 + 100;
    int sb = s0 > len ? s0 : len;
    if (sb >= s1) return;
    int h2 = threadIdx.x * 2;
    const float* vbp = value + (size_t)b * (S_ * H_) + h2;
    float a0 = 0.f, a1 = 0.f;
    for (int s = sb; s < s1; ++s) {
        float2 v = *(const float2*)(vbp + (size_t)s * H_);
        a0 += v.x; a1 += v.y;
    }
    atomicAdd(&maskedT[h2 * B_ + b], a0 * 1e-9f);
    atomicAdd(&maskedT[(h2 + 1) * B_ + b], a1 * 1e-9f);
}

// ================= persistent kernel helpers =================

// load one 128-k chunk for LSTM1 into registers (x = [ctx | emb | h0])
__device__ __forceinline__ void ldA(int c, float4 (&r)[8], const float* cxC,
                                    const float* h0C, const float* emb,
                                    const int* tokl, int tid) {
    int kbase = c * 128;
    if (kbase < 512) {
        const float4* src = (const float4*)(cxC + kbase * B_);
#pragma unroll
        for (int i = 0; i < 8; ++i) r[i] = src[tid + i * 512];
    } else if (kbase >= 768) {
        const float4* src = (const float4*)(h0C + (kbase - 768) * B_);
#pragma unroll
        for (int i = 0; i < 8; ++i) r[i] = src[tid + i * 512];
    } else {
#pragma unroll
        for (int i = 0; i < 8; ++i) {
            int t2 = tid + i * 512, b = t2 & 127, kq = t2 >> 7;
            r[i] = *(const float4*)(emb + (size_t)tokl[b] * E_ + (kbase - 512) + kq * 4);
        }
    }
}

__device__ __forceinline__ void stA(int c, float4 (&r)[8], float* xbuf, int tid) {
    int kbase = c * 128;
    if (kbase < 512 || kbase >= 768) {   // linear [k][b] copy
        float4* dst = (float4*)xbuf;
#pragma unroll
        for (int i = 0; i < 8; ++i) dst[tid + i * 512] = r[i];
    } else {                             // emb: transpose-scatter
#pragma unroll
        for (int i = 0; i < 8; ++i) {
            int t2 = tid + i * 512, b = t2 & 127, kq = t2 >> 7;
            xbuf[(kq * 4 + 0) * B_ + b] = r[i].x;
            xbuf[(kq * 4 + 1) * B_ + b] = r[i].y;
            xbuf[(kq * 4 + 2) * B_ + b] = r[i].z;
            xbuf[(kq * 4 + 3) * B_ + b] = r[i].w;
        }
    }
}

// load one 128-k chunk for LSTM2 (x2 = [h0new | h1prev], both [k][b] linear)
__device__ __forceinline__ void ldB(int c, float4 (&r)[8], const float* h0N,
                                    const float* h1C, int tid) {
    int kbase = c * 128;
    const float4* src = (kbase < 512) ? (const float4*)(h0N + kbase * B_)
                                      : (const float4*)(h1C + (kbase - 512) * B_);
#pragma unroll
    for (int i = 0; i < 8; ++i) r[i] = src[tid + i * 512];
}

__device__ __forceinline__ void stB(float4 (&r)[8], float* xbuf, int tid) {
    float4* dst = (float4*)xbuf;
#pragma unroll
    for (int i = 0; i < 8; ++i) dst[tid + i * 512] = r[i];
}

// per-wave GEMM slice: 16 k of this chunk, 8 rows x 2 b per thread
__device__ __forceinline__ void comp16(const float* WT, int kbase, const float* xbuf,
                                       int lane2, int wslice, float (&acc)[8][2]) {
#pragma unroll
    for (int i = 0; i < 16; ++i) {
        int kk = wslice + i;
        const float* wr = WT + (kbase + kk) * 8;          // wave-uniform -> broadcast
        float4 wa = *(const float4*)wr;
        float4 wb = *(const float4*)(wr + 4);
        float2 xv = *(const float2*)(xbuf + kk * B_ + lane2);
        acc[0][0] += wa.x * xv.x; acc[0][1] += wa.x * xv.y;
        acc[1][0] += wa.y * xv.x; acc[1][1] += wa.y * xv.y;
        acc[2][0] += wa.z * xv.x; acc[2][1] += wa.z * xv.y;
        acc[3][0] += wa.w * xv.x; acc[3][1] += wa.w * xv.y;
        acc[4][0] += wb.x * xv.x; acc[4][1] += wb.x * xv.y;
        acc[5][0] += wb.y * xv.x; acc[5][1] += wb.y * xv.y;
        acc[6][0] += wb.z * xv.x; acc[6][1] += wb.z * xv.y;
        acc[7][0] += wb.w * xv.x; acc[7][1] += wb.w * xv.y;
    }
}

// cross-wave K-reduction + bias + LSTM cell update; writes hT (and optional hn)
__device__ __forceinline__ void redfin(float (&acc)[8][2], float* xbuf,
                                       const float* biasl, int boff, float* cl,
                                       float* hTdst, float* hndst,
                                       int bid, int tid, int wv, int lane) {
    __syncthreads();                       // all waves done reading xbuf
    float* scr = xbuf + wv * 1024;
#pragma unroll
    for (int r = 0; r < 8; ++r)
        *(float2*)&scr[r * 128 + lane * 2] = make_float2(acc[r][0], acc[r][1]);
    __syncthreads();
#pragma unroll
    for (int j = 0; j < 2; ++j) {
        int o = tid * 2 + j;
        float s = 0.f;
#pragma unroll
        for (int w = 0; w < 8; ++w) s += xbuf[w * 1024 + o];
        xbuf[8192 + o] = s;                // gsum region, disjoint from scratch
    }
    __syncthreads();
    if (tid < 256) {
        int hl = tid >> 7, b = tid & 127;
        float g0 = xbuf[8192 + (0 * 2 + hl) * 128 + b] + biasl[boff + 0 * 2 + hl];
        float g1 = xbuf[8192 + (1 * 2 + hl) * 128 + b] + biasl[boff + 1 * 2 + hl];
        float g2 = xbuf[8192 + (2 * 2 + hl) * 128 + b] + biasl[boff + 2 * 2 + hl];
        float g3 = xbuf[8192 + (3 * 2 + hl) * 128 + b] + biasl[boff + 3 * 2 + hl];
        float ii = sigf(g0), ff = sigf(g1), gg = tanhf(g2), oo = sigf(g3);
        float cn = ff * cl[hl * 128 + b] + ii * gg;
        cl[hl * 128 + b] = cn;
        float hn = oo * tanhf(cn);
        int hg = bid * 2 + hl;
        hTdst[hg * B_ + b] = hn;           // transposed layout, coalesced rows
        if (hndst) hndst[b * H_ + hg] = hn; // natural layout for attention
    }
}

// ================= the persistent cooperative kernel =================
__global__ __launch_bounds__(512) void k_run(
    const float* __restrict__ key, const float* __restrict__ value,
    const int* __restrict__ decode, const int* __restrict__ lens,
    const float* __restrict__ emb,
    const float* __restrict__ Wih1, const float* __restrict__ Whh1, const float* __restrict__ b1v,
    const float* __restrict__ Wih2, const float* __restrict__ Whh2, const float* __restrict__ b2v,
    const float* __restrict__ fcW, const float* __restrict__ fcb,
    float* __restrict__ out,
    float* __restrict__ scores, float* __restrict__ cxT, float* __restrict__ h0T,
    float* __restrict__ h1T, float* __restrict__ h1n, const float* __restrict__ maskedT,
    const unsigned short* __restrict__ kb, const unsigned short* __restrict__ vbp,
    int use_bf16) {

    __shared__ float W1T[1280 * 8];        // 40 KiB  [k][8 rows]
    __shared__ float W2T[1024 * 8];        // 32 KiB
    __shared__ float xbuf[128 * 128];      // 64 KiB  chunk / scratch / sl,el,rc
    __shared__ float c0l[256], c1l[256];   // cell state, block-local
    __shared__ float biasl[16];
    __shared__ float redl[16];
    __shared__ int   tokl[128];

    cg::grid_group grid = cg::this_grid();
    const int tid  = threadIdx.x;
    const int bid  = blockIdx.x;           // 0..255
    const int wv   = tid >> 6;
    const int lane = tid & 63;
    const int lane2 = lane * 2;

    // ---- one-time: fill transposed weight slices + bias, zero cell state ----
    {
        const int hg0 = bid * 2;
        for (int r = 0; r < 8; ++r) {
            int gate = r >> 1, hl = r & 1;
            int grow = gate * H_ + hg0 + hl;
            for (int k = tid; k < 1280; k += 512) {
                float w = (k < 768) ? Wih1[(size_t)grow * 768 + k]
                                    : Whh1[(size_t)grow * 512 + (k - 768)];
                W1T[k * 8 + r] = w;
            }
            for (int k = tid; k < 1024; k += 512) {
                float w = (k < 512) ? Wih2[(size_t)grow * 512 + k]
                                    : Whh2[(size_t)grow * 512 + (k - 512)];
                W2T[k * 8 + r] = w;
            }
            if (tid == 0) { biasl[r] = b1v[grow]; biasl[8 + r] = b2v[grow]; }
        }
        if (tid < 256) { c0l[tid] = 0.f; c1l[tid] = 0.f; }
        __syncthreads();
    }

    const int b_att = bid >> 1;            // phase C/D: batch element
    const int sh    = bid & 1;             // s-half
    const int s0a   = sh * 400;
    const int len   = lens[b_att];

    for (int t = 0; t < T_; ++t) {
        const int cur = t & 1, nxt = cur ^ 1;
        const float* cxC = cxT + cur * ST_;
        float*       cxN = cxT + nxt * ST_;
        const float* h0C = h0T + cur * ST_;
        float*       h0N = h0T + nxt * ST_;
        const float* h1C = h1T + cur * ST_;
        float*       h1N = h1T + nxt * ST_;

        // ================= phase A: LSTM1 =================
        if (tid < 128) tokl[tid] = decode[tid * T_ + t];
        float acc[8][2];
#pragma unroll
        for (int r = 0; r < 8; ++r) { acc[r][0] = 0.f; acc[r][1] = 0.f; }
        float4 rg[8];
        ldA(0, rg, cxC, h0C, emb, tokl, tid);
        for (int c = 0; c < 10; ++c) {
            __syncthreads();                       // xbuf free
            stA(c, rg, xbuf, tid);
            if (c < 9) ldA(c + 1, rg, cxC, h0C, emb, tokl, tid);
            __syncthreads();                       // xbuf ready
            comp16(W1T, c * 128, xbuf, lane2, wv * 16, acc);
        }
        redfin(acc, xbuf, biasl, 0, c0l, h0N, nullptr, bid, tid, wv, lane);
        grid.sync();

        // ================= phase B: LSTM2 =================
#pragma unroll
        for (int r = 0; r < 8; ++r) { acc[r][0] = 0.f; acc[r][1] = 0.f; }
        ldB(0, rg, h0N, h1C, tid);
        for (int c = 0; c < 8; ++c) {
            __syncthreads();
            stB(rg, xbuf, tid);
            if (c < 7) ldB(c + 1, rg, h0N, h1C, tid);
            __syncthreads();
            comp16(W2T, c * 128, xbuf, lane2, wv * 16, acc);
        }
        redfin(acc, xbuf, biasl, 8, c1l, h1N, h1n, bid, tid, wv, lane);
        grid.sync();

        // ================= phase C: scores + logits + ctx init =================
        if (tid < 256) cxN[bid * 256 + tid] = maskedT[bid * 256 + tid];
        float4 ha = *(const float4*)(h1n + b_att * H_ + lane * 8);
        float4 hb = *(const float4*)(h1n + b_att * H_ + lane * 8 + 4);
        if (use_bf16) {
            const unsigned short* kbb = kb + (size_t)(b_att * S_) * H_;
            for (int ss = 0; ss < 50; ss += 2) {
                int s1 = s0a + wv * 50 + ss;
                uint4 k1 = *(const uint4*)(kbb + (size_t)s1 * H_ + lane * 8);
                uint4 k2 = *(const uint4*)(kbb + (size_t)(s1 + 1) * H_ + lane * 8);
                float d1 = bdot(k1, ha, hb);
                float d2 = bdot(k2, ha, hb);
#pragma unroll
                for (int m = 32; m; m >>= 1) { d1 += __shfl_xor(d1, m); d2 += __shfl_xor(d2, m); }
                if (lane == 0) {
                    scores[b_att * S_ + s1] = d1;
                    scores[b_att * S_ + s1 + 1] = d2;
                }
            }
        } else {
            const float* kf = key + (size_t)b_att * (S_ * H_);
            for (int ss = 0; ss < 50; ss += 2) {
                int s1 = s0a + wv * 50 + ss;
                const float* r1 = kf + (size_t)s1 * H_ + lane * 8;
                const float* r2 = kf + (size_t)(s1 + 1) * H_ + lane * 8;
                float d1 = dot8(*(const float4*)r1, *(const float4*)(r1 + 4), ha, hb);
                float d2 = dot8(*(const float4*)r2, *(const float4*)(r2 + 4), ha, hb);
#pragma unroll
                for (int m = 32; m; m >>= 1) { d1 += __shfl_xor(d1, m); d2 += __shfl_xor(d2, m); }
                if (lane == 0) {
                    scores[b_att * S_ + s1] = d1;
                    scores[b_att * S_ + s1 + 1] = d2;
                }
            }
        }
        if (sh) {   // logits for this b
            for (int v = wv; v < V_; v += 8) {
                const float* fr = fcW + (size_t)v * H_ + lane * 8;
                float d = dot8(*(const float4*)fr, *(const float4*)(fr + 4), ha, hb);
#pragma unroll
                for (int m = 32; m; m >>= 1) d += __shfl_xor(d, m);
                if (lane == 0) out[(size_t)b_att * (T_ * V_) + t * V_ + v] = d + fcb[v];
            }
        }
        grid.sync();

        // ================= phase D: softmax + context =================
        {
            float* sl = xbuf;              // [800]
            float* el = xbuf + 800;        // [400]
            float* rc = xbuf + 1216;       // [8][512], 16B-aligned
            float v0 = scores[b_att * S_ + tid];
            float v1 = (tid < 288) ? scores[b_att * S_ + 512 + tid] : -INFINITY;
            sl[tid] = v0;
            if (tid < 288) sl[512 + tid] = v1;
            float mx = fmaxf(v0, v1);
#pragma unroll
            for (int m = 32; m; m >>= 1) mx = fmaxf(mx, __shfl_xor(mx, m));
            if (lane == 0) redl[wv] = mx;
            __syncthreads();
            mx = redl[0];
#pragma unroll
            for (int w = 1; w < 8; ++w) mx = fmaxf(mx, redl[w]);
            float sm = expf(v0 - mx) + ((tid < 288) ? expf(v1 - mx) : 0.f);
#pragma unroll
            for (int m = 32; m; m >>= 1) sm += __shfl_xor(sm, m);
            if (lane == 0) redl[8 + wv] = sm;
            __syncthreads();
            sm = redl[8] + redl[9] + redl[10] + redl[11] +
                 redl[12] + redl[13] + redl[14] + redl[15];
            float inv = 1.f / sm;
            if (tid < 400) {
                int s = s0a + tid;
                el[tid] = (s < len) ? expf(sl[s] - mx) * inv : 0.f;
            }
            __syncthreads();

            float ac0=0.f,ac1=0.f,ac2=0.f,ac3=0.f,ac4=0.f,ac5=0.f,ac6=0.f,ac7=0.f;
            if (use_bf16) {
                const unsigned short* vbb = vbp + (size_t)(b_att * S_) * H_ + lane * 8;
                for (int sp = wv; sp < 400; sp += 8) {
                    float e = el[sp];                       // wave-uniform
                    if (e != 0.f) {
                        uint4 v4 = *(const uint4*)(vbb + (size_t)(s0a + sp) * H_);
                        ac0 += e * __uint_as_float(v4.x << 16);
                        ac1 += e * __uint_as_float(v4.x & 0xffff0000u);
                        ac2 += e * __uint_as_float(v4.y << 16);
                        ac3 += e * __uint_as_float(v4.y & 0xffff0000u);
                        ac4 += e * __uint_as_float(v4.z << 16);
                        ac5 += e * __uint_as_float(v4.z & 0xffff0000u);
                        ac6 += e * __uint_as_float(v4.w << 16);
                        ac7 += e * __uint_as_float(v4.w & 0xffff0000u);
                    }
                }
            } else {
                const float* vf = value + (size_t)b_att * (S_ * H_) + lane * 8;
                for (int sp = wv; sp < 400; sp += 8) {
                    float e = el[sp];
                    if (e != 0.f) {
                        const float* vr = vf + (size_t)(s0a + sp) * H_;
                        float4 va = *(const float4*)vr;
                        float4 vb4 = *(const float4*)(vr + 4);
                        ac0 += e * va.x; ac1 += e * va.y; ac2 += e * va.z; ac3 += e * va.w;
                        ac4 += e * vb4.x; ac5 += e * vb4.y; ac6 += e * vb4.z; ac7 += e * vb4.w;
                    }
                }
            }
            *(float4*)&rc[wv * H_ + lane * 8]     = make_float4(ac0, ac1, ac2, ac3);
            *(float4*)&rc[wv * H_ + lane * 8 + 4] = make_float4(ac4, ac5, ac6, ac7);
            __syncthreads();
            float s8 = 0.f;
#pragma unroll
            for (int w = 0; w < 8; ++w) s8 += rc[w * H_ + tid];
            atomicAdd(&cxN[tid * B_ + b_att], s8);
        }
        grid.sync();
    }
}

} // anonymous namespace

extern "C" void kernel_launch(void* const* d_in, const int* in_sizes, int n_in,
                              void* d_out, int out_size, void* d_ws, size_t ws_size,
                              hipStream_t stream) {
    const float* key    = (const float*)d_in[0];
    const float* value  = (const float*)d_in[1];
    const int*   decode = (const int*)d_in[2];
    const int*   lens   = (const int*)d_in[3];
    const float* emb    = (const float*)d_in[4];
    const float* Wih1   = (const float*)d_in[5];
    const float* Whh1   = (const float*)d_in[6];
    const float* b1v    = (const float*)d_in[7];
    const float* Wih2   = (const float*)d_in[8];
    const float* Whh2   = (const float*)d_in[9];
    const float* b2v    = (const float*)d_in[10];
    const float* fcW    = (const float*)d_in[11];
    const float* fcb    = (const float*)d_in[12];
    float* out = (float*)d_out;

    float* p = (float*)d_ws;
    float* scores  = p; p += B_ * S_;
    float* cxT     = p; p += 2 * ST_;
    float* h0T     = p; p += 2 * ST_;
    float* h1T     = p; p += 2 * ST_;
    float* h1n     = p; p += ST_;
    float* maskedT = p; p += ST_;
    unsigned short* kb = (unsigned short*)p;
    unsigned short* vb = kb + KV_;
    size_t need = (size_t)((char*)(vb + KV_) - (char*)d_ws);
    int use_bf16 = (ws_size >= need) ? 1 : 0;

    if (use_bf16) k_pre<<<2048, 256, 0, stream>>>(key, value, kb, vb);
    k_init2<<<256, 256, 0, stream>>>(key, cxT, h0T, h1T, maskedT);
    k_maskT<<<dim3(8, B_), 256, 0, stream>>>(value, lens, maskedT);

    void* args[] = {
        (void*)&key, (void*)&value, (void*)&decode, (void*)&lens, (void*)&emb,
        (void*)&Wih1, (void*)&Whh1, (void*)&b1v, (void*)&Wih2, (void*)&Whh2,
        (void*)&b2v, (void*)&fcW, (void*)&fcb, (void*)&out,
        (void*)&scores, (void*)&cxT, (void*)&h0T, (void*)&h1T, (void*)&h1n,
        (void*)&maskedT, (void*)&kb, (void*)&vb, (void*)&use_bf16
    };
    hipLaunchCooperativeKernel((const void*)k_run, dim3(256), dim3(512),
                               args, 0, stream);
}

// Round 4
// 21748.642 us; speedup vs baseline: 1.3655x; 1.2697x over previous
//
#include <hip/hip_runtime.h>
#include <math.h>

namespace {

constexpr int B_ = 128, S_ = 800, H_ = 512, E_ = 256, V_ = 34, T_ = 128;
constexpr int KV_ = B_ * S_ * H_;          // 52428800 elements
constexpr int ST_ = H_ * B_;               // 65536 floats per state buffer

__device__ __forceinline__ float sigf(float x) { return 1.f / (1.f + expf(-x)); }

__device__ __forceinline__ float dot8(float4 a0, float4 a1, float4 b0, float4 b1) {
    return a0.x * b0.x + a0.y * b0.y + a0.z * b0.z + a0.w * b0.w +
           a1.x * b1.x + a1.y * b1.y + a1.z * b1.z + a1.w * b1.w;
}

__device__ __forceinline__ unsigned short f2bf(float f) {   // round-to-nearest-even
    unsigned u = __float_as_uint(f);
    return (unsigned short)((u + 0x7fffu + ((u >> 16) & 1u)) >> 16);
}

__device__ __forceinline__ float bdot(uint4 k, float4 ha, float4 hb) {
    float d;
    d  = __uint_as_float(k.x << 16) * ha.x + __uint_as_float(k.x & 0xffff0000u) * ha.y;
    d += __uint_as_float(k.y << 16) * ha.z + __uint_as_float(k.y & 0xffff0000u) * ha.w;
    d += __uint_as_float(k.z << 16) * hb.x + __uint_as_float(k.z & 0xffff0000u) * hb.y;
    d += __uint_as_float(k.w << 16) * hb.z + __uint_as_float(k.w & 0xffff0000u) * hb.w;
    return d;
}

// ---------- fast grid barrier: monotonic counter, relaxed spin ----------
__device__ __forceinline__ void gbar(unsigned* bar, unsigned target) {
    __syncthreads();                       // drains all waves' vmem (vmcnt0 before s_barrier)
    if (threadIdx.x == 0) {
        __threadfence();                   // release: L2 writeback, agent scope
        __hip_atomic_fetch_add(bar, 1u, __ATOMIC_RELAXED, __HIP_MEMORY_SCOPE_AGENT);
        while (__hip_atomic_load(bar, __ATOMIC_RELAXED, __HIP_MEMORY_SCOPE_AGENT) < target) {
            __builtin_amdgcn_s_sleep(1);
        }
        __threadfence();                   // acquire: invalidate L1/L2
    }
    __syncthreads();
}

// ---------- pre-pass: fp32 -> bf16 key/value ----------
__global__ __launch_bounds__(256) void k_pre(const float* __restrict__ key,
                                             const float* __restrict__ value,
                                             unsigned short* __restrict__ kb,
                                             unsigned short* __restrict__ vb) {
    const int n4 = KV_ / 4;
    for (int i = blockIdx.x * 256 + threadIdx.x; i < n4; i += gridDim.x * 256) {
        float4 k4 = ((const float4*)key)[i];
        float4 v4 = ((const float4*)value)[i];
        ushort4 ko, vo;
        ko.x = f2bf(k4.x); ko.y = f2bf(k4.y); ko.z = f2bf(k4.z); ko.w = f2bf(k4.w);
        vo.x = f2bf(v4.x); vo.y = f2bf(v4.y); vo.z = f2bf(v4.z); vo.w = f2bf(v4.w);
        ((ushort4*)kb)[i] = ko;
        ((ushort4*)vb)[i] = vo;
    }
}

// ---------- pre-pass: state init ----------
__global__ __launch_bounds__(256) void k_init3(const float* __restrict__ key,
                                               float* __restrict__ P0T, float* __restrict__ P1T,
                                               float* __restrict__ h0T, float* __restrict__ h1T,
                                               float* __restrict__ maskedT,
                                               float* __restrict__ rec,
                                               unsigned* __restrict__ bar) {
    int i = blockIdx.x * 256 + threadIdx.x;     // 0..65535
    int b = i >> 9, h = i & 511;
    P0T[h * B_ + b] = key[(size_t)b * (S_ * H_) + h];   // ctx0 = key[:,0,:] (transposed)
    P1T[i] = 0.f;
    h0T[i] = 0.f; h0T[ST_ + i] = 0.f;
    h1T[i] = 0.f; h1T[ST_ + i] = 0.f;
    maskedT[i] = 0.f;
    if (i < 512) rec[i] = 0.f;
    if (i < 16) bar[i] = 0u;
}

// ---------- pre-pass: maskedT[h][b] = 1e-9 * sum_{s>=len} value[b][s][h] ----------
__global__ __launch_bounds__(256) void k_maskT(const float* __restrict__ value,
                                               const int* __restrict__ lens,
                                               float* __restrict__ maskedT) {
    int strip = blockIdx.x, b = blockIdx.y;
    int len = lens[b];
    int s0 = strip * 100, s1 = s0 + 100;
    int sb = s0 > len ? s0 : len;
    if (sb >= s1) return;
    int h2 = threadIdx.x * 2;
    const float* vbp = value + (size_t)b * (S_ * H_) + h2;
    float a0 = 0.f, a1 = 0.f;
    for (int s = sb; s < s1; ++s) {
        float2 v = *(const float2*)(vbp + (size_t)s * H_);
        a0 += v.x; a1 += v.y;
    }
    atomicAdd(&maskedT[h2 * B_ + b], a0 * 1e-9f);
    atomicAdd(&maskedT[(h2 + 1) * B_ + b], a1 * 1e-9f);
}

// ================= persistent kernel helpers =================

// load one 128-k chunk for LSTM1; ctx range applies softmax finalize on the fly
__device__ __forceinline__ void ldA(int c, float4 (&r)[8],
                                    const float* __restrict__ P0T,
                                    const float* __restrict__ P1T,
                                    const float* __restrict__ maskedT,
                                    const float* __restrict__ h0C,
                                    const float* __restrict__ emb,
                                    const int* tokl, int tid,
                                    float4 a4, float4 b4, bool addm) {
    int kbase = c * 128;
    if (kbase < 512) {                     // ctx = alpha*P0 + beta*P1 (+ masked)
        const float4* p0 = (const float4*)P0T + kbase * 32;
        const float4* p1 = (const float4*)P1T + kbase * 32;
        const float4* pm = (const float4*)maskedT + kbase * 32;
#pragma unroll
        for (int i = 0; i < 8; ++i) {
            int f = tid + i * 512;
            float4 v0 = p0[f], v1 = p1[f];
            float4 x;
            x.x = a4.x * v0.x + b4.x * v1.x;
            x.y = a4.y * v0.y + b4.y * v1.y;
            x.z = a4.z * v0.z + b4.z * v1.z;
            x.w = a4.w * v0.w + b4.w * v1.w;
            if (addm) {
                float4 m = pm[f];
                x.x += m.x; x.y += m.y; x.z += m.z; x.w += m.w;
            }
            r[i] = x;
        }
    } else if (kbase >= 768) {             // h0 (transposed, linear)
        const float4* src = (const float4*)(h0C + (kbase - 768) * B_);
#pragma unroll
        for (int i = 0; i < 8; ++i) r[i] = src[tid + i * 512];
    } else {                               // emb gather (natural)
#pragma unroll
        for (int i = 0; i < 8; ++i) {
            int t2 = tid + i * 512, b = t2 & 127, kq = t2 >> 7;
            r[i] = *(const float4*)(emb + (size_t)tokl[b] * E_ + (kbase - 512) + kq * 4);
        }
    }
}

__device__ __forceinline__ void stA(int c, float4 (&r)[8], float* xbuf, int tid) {
    int kbase = c * 128;
    if (kbase < 512 || kbase >= 768) {     // linear [k][b] copy
        float4* dst = (float4*)xbuf;
#pragma unroll
        for (int i = 0; i < 8; ++i) dst[tid + i * 512] = r[i];
    } else {                               // emb: transpose-scatter
#pragma unroll
        for (int i = 0; i < 8; ++i) {
            int t2 = tid + i * 512, b = t2 & 127, kq = t2 >> 7;
            xbuf[(kq * 4 + 0) * B_ + b] = r[i].x;
            xbuf[(kq * 4 + 1) * B_ + b] = r[i].y;
            xbuf[(kq * 4 + 2) * B_ + b] = r[i].z;
            xbuf[(kq * 4 + 3) * B_ + b] = r[i].w;
        }
    }
}

// load one 128-k chunk for LSTM2 (x2 = [h0new | h1prev], both [k][b] linear)
__device__ __forceinline__ void ldB(int c, float4 (&r)[8], const float* h0N,
                                    const float* h1C, int tid) {
    int kbase = c * 128;
    const float4* src = (kbase < 512) ? (const float4*)(h0N + kbase * B_)
                                      : (const float4*)(h1C + (kbase - 512) * B_);
#pragma unroll
    for (int i = 0; i < 8; ++i) r[i] = src[tid + i * 512];
}

__device__ __forceinline__ void stB(float4 (&r)[8], float* xbuf, int tid) {
    float4* dst = (float4*)xbuf;
#pragma unroll
    for (int i = 0; i < 8; ++i) dst[tid + i * 512] = r[i];
}

// per-wave GEMM slice: 16 k of this chunk, 8 rows x 2 b per thread
__device__ __forceinline__ void comp16(const float* WT, int kbase, const float* xbuf,
                                       int lane2, int wslice, float (&acc)[8][2]) {
#pragma unroll
    for (int i = 0; i < 16; ++i) {
        int kk = wslice + i;
        const float* wr = WT + (kbase + kk) * 8;          // wave-uniform -> broadcast
        float4 wa = *(const float4*)wr;
        float4 wb = *(const float4*)(wr + 4);
        float2 xv = *(const float2*)(xbuf + kk * B_ + lane2);
        acc[0][0] += wa.x * xv.x; acc[0][1] += wa.x * xv.y;
        acc[1][0] += wa.y * xv.x; acc[1][1] += wa.y * xv.y;
        acc[2][0] += wa.z * xv.x; acc[2][1] += wa.z * xv.y;
        acc[3][0] += wa.w * xv.x; acc[3][1] += wa.w * xv.y;
        acc[4][0] += wb.x * xv.x; acc[4][1] += wb.x * xv.y;
        acc[5][0] += wb.y * xv.x; acc[5][1] += wb.y * xv.y;
        acc[6][0] += wb.z * xv.x; acc[6][1] += wb.z * xv.y;
        acc[7][0] += wb.w * xv.x; acc[7][1] += wb.w * xv.y;
    }
}

// cross-wave K-reduction + bias + LSTM cell update; writes hT (and optional hn)
__device__ __forceinline__ void redfin(float (&acc)[8][2], float* xbuf,
                                       const float* biasl, int boff, float* cl,
                                       float* hTdst, float* hndst,
                                       int bid, int tid, int wv, int lane) {
    __syncthreads();                       // all waves done reading xbuf
    float* scr = xbuf + wv * 1024;
#pragma unroll
    for (int r = 0; r < 8; ++r)
        *(float2*)&scr[r * 128 + lane * 2] = make_float2(acc[r][0], acc[r][1]);
    __syncthreads();
#pragma unroll
    for (int j = 0; j < 2; ++j) {
        int o = tid * 2 + j;
        float s = 0.f;
#pragma unroll
        for (int w = 0; w < 8; ++w) s += xbuf[w * 1024 + o];
        xbuf[8192 + o] = s;                // gsum region, disjoint from scratch
    }
    __syncthreads();
    if (tid < 256) {
        int hl = tid >> 7, b = tid & 127;
        float g0 = xbuf[8192 + (0 * 2 + hl) * 128 + b] + biasl[boff + 0 * 2 + hl];
        float g1 = xbuf[8192 + (1 * 2 + hl) * 128 + b] + biasl[boff + 1 * 2 + hl];
        float g2 = xbuf[8192 + (2 * 2 + hl) * 128 + b] + biasl[boff + 2 * 2 + hl];
        float g3 = xbuf[8192 + (3 * 2 + hl) * 128 + b] + biasl[boff + 3 * 2 + hl];
        float ii = sigf(g0), ff = sigf(g1), gg = tanhf(g2), oo = sigf(g3);
        float cn = ff * cl[hl * 128 + b] + ii * gg;
        cl[hl * 128 + b] = cn;
        float hn = oo * tanhf(cn);
        int hg = bid * 2 + hl;
        hTdst[hg * B_ + b] = hn;           // transposed layout, coalesced rows
        if (hndst) hndst[b * H_ + hg] = hn; // natural layout for attention
    }
}

// ================= the persistent cooperative kernel =================
__global__ __launch_bounds__(512) void k_run(
    const float* __restrict__ key, const float* __restrict__ value,
    const int* __restrict__ decode, const int* __restrict__ lens,
    const float* __restrict__ emb,
    const float* __restrict__ Wih1, const float* __restrict__ Whh1, const float* __restrict__ b1v,
    const float* __restrict__ Wih2, const float* __restrict__ Whh2, const float* __restrict__ b2v,
    const float* __restrict__ fcW, const float* __restrict__ fcb,
    float* __restrict__ out,
    unsigned* __restrict__ bar, float* __restrict__ rec,
    float* __restrict__ P0T, float* __restrict__ P1T, const float* __restrict__ maskedT,
    float* __restrict__ h0T, float* __restrict__ h1T, float* __restrict__ h1n,
    const unsigned short* __restrict__ kb, const unsigned short* __restrict__ vbp,
    int use_bf16) {

    __shared__ float W1T[1280 * 8];        // 40 KiB  [k][8 rows]
    __shared__ float W2T[1024 * 8];        // 32 KiB
    __shared__ float xbuf[128 * 128];      // 64 KiB  chunk / scratch / attn overlay
    __shared__ float c0l[256], c1l[256];   // cell state, block-local
    __shared__ float biasl[16];
    __shared__ float redl[16];
    __shared__ float alf[128], bet[128];
    __shared__ int   tokl[128];

    const int tid  = threadIdx.x;
    const int bid  = blockIdx.x;           // 0..255
    const int wv   = tid >> 6;
    const int lane = tid & 63;
    const int lane2 = lane * 2;
    unsigned barcnt = 0;

    // ---- one-time: fill transposed weight slices + bias, zero cell state ----
    {
        const int hg0 = bid * 2;
        for (int r = 0; r < 8; ++r) {
            int gate = r >> 1, hl = r & 1;
            int grow = gate * H_ + hg0 + hl;
            for (int k = tid; k < 1280; k += 512) {
                float w = (k < 768) ? Wih1[(size_t)grow * 768 + k]
                                    : Whh1[(size_t)grow * 512 + (k - 768)];
                W1T[k * 8 + r] = w;
            }
            for (int k = tid; k < 1024; k += 512) {
                float w = (k < 512) ? Wih2[(size_t)grow * 512 + k]
                                    : Whh2[(size_t)grow * 512 + (k - 512)];
                W2T[k * 8 + r] = w;
            }
            if (tid == 0) { biasl[r] = b1v[grow]; biasl[8 + r] = b2v[grow]; }
        }
        if (tid < 256) { c0l[tid] = 0.f; c1l[tid] = 0.f; }
        __syncthreads();
    }

    const int b_att = bid >> 1;            // attention: batch element
    const int sh    = bid & 1;             // s-half (0: rows 0-399, 1: 400-799)
    const int s0a   = sh * 400;
    const int len   = lens[b_att];

    for (int t = 0; t < T_; ++t) {
        const int cur = t & 1, nxt = cur ^ 1;
        const float* h0C = h0T + cur * ST_;
        float*       h0N = h0T + nxt * ST_;
        const float* h1C = h1T + cur * ST_;
        float*       h1N = h1T + nxt * ST_;

        // ================= phase A: LSTM1 (ctx finalize fused into staging) ======
        if (tid < 128) {
            tokl[tid] = decode[tid * T_ + t];
            if (t > 0) {
                float4 rr = *(const float4*)(rec + tid * 4);    // mx0,s0,mx1,s1
                float M  = fmaxf(rr.x, rr.z);
                float e0 = expf(rr.x - M), e1 = expf(rr.z - M);
                float den = rr.y * e0 + rr.w * e1;
                alf[tid] = e0 / den; bet[tid] = e1 / den;
            } else { alf[tid] = 1.f; bet[tid] = 0.f; }
        }
        __syncthreads();
        const float4 a4 = *(const float4*)&alf[(tid & 31) * 4];
        const float4 b4 = *(const float4*)&bet[(tid & 31) * 4];
        const bool addm = (t > 0);

        float acc[8][2];
#pragma unroll
        for (int r = 0; r < 8; ++r) { acc[r][0] = 0.f; acc[r][1] = 0.f; }
        float4 rg[8];
        ldA(0, rg, P0T, P1T, maskedT, h0C, emb, tokl, tid, a4, b4, addm);
        for (int c = 0; c < 10; ++c) {
            __syncthreads();                       // xbuf free
            stA(c, rg, xbuf, tid);
            if (c < 9) ldA(c + 1, rg, P0T, P1T, maskedT, h0C, emb, tokl, tid, a4, b4, addm);
            __syncthreads();                       // xbuf ready
            comp16(W1T, c * 128, xbuf, lane2, wv * 16, acc);
        }
        redfin(acc, xbuf, biasl, 0, c0l, h0N, nullptr, bid, tid, wv, lane);
        gbar(bar, barcnt += 256);

        // ================= phase B: LSTM2 =================
#pragma unroll
        for (int r = 0; r < 8; ++r) { acc[r][0] = 0.f; acc[r][1] = 0.f; }
        ldB(0, rg, h0N, h1C, tid);
        for (int c = 0; c < 8; ++c) {
            __syncthreads();
            stB(rg, xbuf, tid);
            if (c < 7) ldB(c + 1, rg, h0N, h1C, tid);
            __syncthreads();
            comp16(W2T, c * 128, xbuf, lane2, wv * 16, acc);
        }
        redfin(acc, xbuf, biasl, 8, c1l, h1N, h1n, bid, tid, wv, lane);
        gbar(bar, barcnt += 256);

        // ====== phase CD: scores + local softmax + partial context + logits ======
        {
            float* sl2 = xbuf;             // [400]
            float* el2 = xbuf + 512;       // [400]
            float* rc  = xbuf + 1024;      // [8][512]
            float4 ha = *(const float4*)(h1n + (size_t)b_att * H_ + lane * 8);
            float4 hb = *(const float4*)(h1n + (size_t)b_att * H_ + lane * 8 + 4);
            if (use_bf16) {
                const unsigned short* kbb = kb + (size_t)b_att * (S_ * H_);
                for (int ss = 0; ss < 50; ss += 2) {
                    int sl_ = wv * 50 + ss;
                    int s1 = s0a + sl_;
                    uint4 k1 = *(const uint4*)(kbb + (size_t)s1 * H_ + lane * 8);
                    uint4 k2 = *(const uint4*)(kbb + (size_t)(s1 + 1) * H_ + lane * 8);
                    float d1 = bdot(k1, ha, hb);
                    float d2 = bdot(k2, ha, hb);
#pragma unroll
                    for (int m = 32; m; m >>= 1) { d1 += __shfl_xor(d1, m); d2 += __shfl_xor(d2, m); }
                    if (lane == 0) { sl2[sl_] = d1; sl2[sl_ + 1] = d2; }
                }
            } else {
                const float* kf = key + (size_t)b_att * (S_ * H_);
                for (int ss = 0; ss < 50; ss += 2) {
                    int sl_ = wv * 50 + ss;
                    int s1 = s0a + sl_;
                    const float* r1 = kf + (size_t)s1 * H_ + lane * 8;
                    const float* r2 = kf + (size_t)(s1 + 1) * H_ + lane * 8;
                    float d1 = dot8(*(const float4*)r1, *(const float4*)(r1 + 4), ha, hb);
                    float d2 = dot8(*(const float4*)r2, *(const float4*)(r2 + 4), ha, hb);
#pragma unroll
                    for (int m = 32; m; m >>= 1) { d1 += __shfl_xor(d1, m); d2 += __shfl_xor(d2, m); }
                    if (lane == 0) { sl2[sl_] = d1; sl2[sl_ + 1] = d2; }
                }
            }
            __syncthreads();
            // local max over this half's 400 scores
            float v0 = (tid < 400) ? sl2[tid] : -INFINITY;
            float mx = v0;
#pragma unroll
            for (int m = 32; m; m >>= 1) mx = fmaxf(mx, __shfl_xor(mx, m));
            if (lane == 0) redl[wv] = mx;
            __syncthreads();
            mx = redl[0];
#pragma unroll
            for (int w = 1; w < 8; ++w) mx = fmaxf(mx, redl[w]);
            float e = (tid < 400) ? expf(v0 - mx) : 0.f;
            float sm = e;
#pragma unroll
            for (int m = 32; m; m >>= 1) sm += __shfl_xor(sm, m);
            if (lane == 0) redl[8 + wv] = sm;
            __syncthreads();
            sm = redl[8] + redl[9] + redl[10] + redl[11] +
                 redl[12] + redl[13] + redl[14] + redl[15];
            if (tid == 0) {
                rec[b_att * 4 + sh * 2]     = mx;
                rec[b_att * 4 + sh * 2 + 1] = sm;
            }
            if (tid < 400) el2[tid] = (s0a + tid < len) ? e : 0.f;   // UNNORMALIZED
            __syncthreads();

            float ac0=0.f,ac1=0.f,ac2=0.f,ac3=0.f,ac4=0.f,ac5=0.f,ac6=0.f,ac7=0.f;
            if (use_bf16) {
                const unsigned short* vbb = vbp + (size_t)b_att * (S_ * H_) + lane * 8;
                for (int sp = wv; sp < 400; sp += 8) {
                    float ew = el2[sp];                    // wave-uniform
                    if (ew != 0.f) {
                        uint4 v4 = *(const uint4*)(vbb + (size_t)(s0a + sp) * H_);
                        ac0 += ew * __uint_as_float(v4.x << 16);
                        ac1 += ew * __uint_as_float(v4.x & 0xffff0000u);
                        ac2 += ew * __uint_as_float(v4.y << 16);
                        ac3 += ew * __uint_as_float(v4.y & 0xffff0000u);
                        ac4 += ew * __uint_as_float(v4.z << 16);
                        ac5 += ew * __uint_as_float(v4.z & 0xffff0000u);
                        ac6 += ew * __uint_as_float(v4.w << 16);
                        ac7 += ew * __uint_as_float(v4.w & 0xffff0000u);
                    }
                }
            } else {
                const float* vf = value + (size_t)b_att * (S_ * H_) + lane * 8;
                for (int sp = wv; sp < 400; sp += 8) {
                    float ew = el2[sp];
                    if (ew != 0.f) {
                        const float* vr = vf + (size_t)(s0a + sp) * H_;
                        float4 va = *(const float4*)vr;
                        float4 vb4 = *(const float4*)(vr + 4);
                        ac0 += ew * va.x; ac1 += ew * va.y; ac2 += ew * va.z; ac3 += ew * va.w;
                        ac4 += ew * vb4.x; ac5 += ew * vb4.y; ac6 += ew * vb4.z; ac7 += ew * vb4.w;
                    }
                }
            }
            *(float4*)&rc[wv * H_ + lane * 8]     = make_float4(ac0, ac1, ac2, ac3);
            *(float4*)&rc[wv * H_ + lane * 8 + 4] = make_float4(ac4, ac5, ac6, ac7);
            __syncthreads();
            float s8 = 0.f;
#pragma unroll
            for (int w = 0; w < 8; ++w) s8 += rc[w * H_ + tid];
            float* dst = sh ? P1T : P0T;
            dst[tid * B_ + b_att] = s8;                    // unnormalized partial ctx

            if (sh) {   // logits for this b
                for (int v = wv; v < V_; v += 8) {
                    const float* fr = fcW + (size_t)v * H_ + lane * 8;
                    float d = dot8(*(const float4*)fr, *(const float4*)(fr + 4), ha, hb);
#pragma unroll
                    for (int m = 32; m; m >>= 1) d += __shfl_xor(d, m);
                    if (lane == 0) out[(size_t)b_att * (T_ * V_) + t * V_ + v] = d + fcb[v];
                }
            }
        }
        gbar(bar, barcnt += 256);
    }
}

} // anonymous namespace

extern "C" void kernel_launch(void* const* d_in, const int* in_sizes, int n_in,
                              void* d_out, int out_size, void* d_ws, size_t ws_size,
                              hipStream_t stream) {
    const float* key    = (const float*)d_in[0];
    const float* value  = (const float*)d_in[1];
    const int*   decode = (const int*)d_in[2];
    const int*   lens   = (const int*)d_in[3];
    const float* emb    = (const float*)d_in[4];
    const float* Wih1   = (const float*)d_in[5];
    const float* Whh1   = (const float*)d_in[6];
    const float* b1v    = (const float*)d_in[7];
    const float* Wih2   = (const float*)d_in[8];
    const float* Whh2   = (const float*)d_in[9];
    const float* b2v    = (const float*)d_in[10];
    const float* fcW    = (const float*)d_in[11];
    const float* fcb    = (const float*)d_in[12];
    float* out = (float*)d_out;

    float* p = (float*)d_ws;
    unsigned* bar  = (unsigned*)p; p += 16;
    float* rec     = p; p += 512;
    float* maskedT = p; p += ST_;
    float* P0T     = p; p += ST_;
    float* P1T     = p; p += ST_;
    float* h0T     = p; p += 2 * ST_;
    float* h1T     = p; p += 2 * ST_;
    float* h1n     = p; p += ST_;
    unsigned short* kb = (unsigned short*)p;
    unsigned short* vb = kb + KV_;
    size_t need = (size_t)((char*)(vb + KV_) - (char*)d_ws);
    int use_bf16 = (ws_size >= need) ? 1 : 0;

    if (use_bf16) k_pre<<<2048, 256, 0, stream>>>(key, value, kb, vb);
    k_init3<<<256, 256, 0, stream>>>(key, P0T, P1T, h0T, h1T, maskedT, rec, bar);
    k_maskT<<<dim3(8, B_), 256, 0, stream>>>(value, lens, maskedT);

    void* args[] = {
        (void*)&key, (void*)&value, (void*)&decode, (void*)&lens, (void*)&emb,
        (void*)&Wih1, (void*)&Whh1, (void*)&b1v, (void*)&Wih2, (void*)&Whh2,
        (void*)&b2v, (void*)&fcW, (void*)&fcb, (void*)&out,
        (void*)&bar, (void*)&rec, (void*)&P0T, (void*)&P1T, (void*)&maskedT,
        (void*)&h0T, (void*)&h1T, (void*)&h1n, (void*)&kb, (void*)&vb, (void*)&use_bf16
    };
    hipLaunchCooperativeKernel((const void*)k_run, dim3(256), dim3(512),
                               args, 0, stream);
}